// Round 11
// baseline (109.817 us; speedup 1.0000x reference)
//
#include <hip/hip_runtime.h>
#include <hip/hip_bf16.h>

#define TT 4096
#define SS 4096
#define CC 1024
#define HS 64

typedef __bf16 bf16x8 __attribute__((ext_vector_type(8)));
typedef __bf16 bf16x4 __attribute__((ext_vector_type(4)));
typedef float  f32x4  __attribute__((ext_vector_type(4)));
typedef float  f32x16 __attribute__((ext_vector_type(16)));

#define MFMA16(A,B,C) __builtin_amdgcn_mfma_f32_16x16x32_bf16((A),(B),(C),0,0,0)
#define MFMA32(A,B,C) __builtin_amdgcn_mfma_f32_32x32x16_bf16((A),(B),(C),0,0,0)

__device__ __forceinline__ int pkbf(float a, float b) {
    union { struct { __bf16 lo, hi; } h; int i; } u;
    u.h.lo = (__bf16)a; u.h.hi = (__bf16)b;
    return u.i;
}

__device__ __forceinline__ bf16x8 cvt8(float4 f0, float4 f1) {
    bf16x8 a;
    a[0] = (__bf16)f0.x; a[1] = (__bf16)f0.y; a[2] = (__bf16)f0.z; a[3] = (__bf16)f0.w;
    a[4] = (__bf16)f1.x; a[5] = (__bf16)f1.y; a[6] = (__bf16)f1.z; a[7] = (__bf16)f1.w;
    return a;
}

// fire-and-forget global->LDS, 16B per lane; LDS dest = wave-uniform base + lane*16
__device__ __forceinline__ void gload_lds16(const void* g, char* l) {
    __builtin_amdgcn_global_load_lds(
        (const __attribute__((address_space(1))) void*)g,
        (__attribute__((address_space(3))) void*)l, 16, 0, 0);
}

// ---------------- prep: W[1024][64] fp32 -> WT[64][1024] bf16 --------------------------
__global__ __launch_bounds__(256) void prep_wt(const float* __restrict__ Wq,
                                               const float* __restrict__ Wk,
                                               const float* __restrict__ Wv,
                                               __bf16* __restrict__ wt) {
    int idx = blockIdx.x * 256 + threadIdx.x;   // 3*65536 total
    int mat = idx >> 16;
    int e   = idx & 65535;
    int d   = e >> 10;
    int kk  = e & 1023;
    const float* W = (mat == 0) ? Wq : (mat == 1 ? Wk : Wv);
    float v = W[kk * HS + d];
    if (mat == 0) v *= 0.125f * 1.44269504088896340736f;
    wt[idx] = (__bf16)v;                        // wt[mat][d][kk]
}

// ---------------- QKV projection: K-split x2, 16 waves/CU, barrier-free K-loop ---------
// 512 blocks x 512 thr. bid&1: 0 -> q from x, 1 -> k+v from enc. Block = 64 rows.
// Wave (rg=w>>1, kh=w&1): rows [rowbase, rowbase+16), K-half kh*512, 8 steps of 64.
// A: wave-private LDS dbuf (2x32KB total) via gload_lds (swizzle verified R6-R10).
// B: flat register loads issued BEFORE next-tile staging, so compiler B-waits
// (in-order vmcnt) do not drain stage(s+1); manual vmcnt(nB+4) drains stage(s).
// NO barriers in the K-loop. Epilogue: kh=1 waves dump accs to LDS, kh=0 combine+store.
__global__ __launch_bounds__(512, 4) void proj_qkv(const float* __restrict__ x,
                                                   const float* __restrict__ enc,
                                                   const __bf16* __restrict__ wt,
                                                   __bf16* __restrict__ qb,
                                                   __bf16* __restrict__ kb,
                                                   __bf16* __restrict__ vt) {
    extern __shared__ char smem[];              // 65536: A dbuf 2x32KB
    int tid = threadIdx.x;
    int w = tid >> 6, l = tid & 63, lq = l >> 4, lm = l & 15;
    int rg = w >> 1, kh = w & 1;
    int kv   = blockIdx.x & 1;
    int row0 = (blockIdx.x >> 1) * 64;
    int rowbase = row0 + rg * 16;
    int kbase0  = kh * 512;
    const float*  src = kv ? enc : x;
    const __bf16* wA  = wt + (kv ? HS * CC : 0);
    const __bf16* wV  = wt + 2 * HS * CC;

    // A-stage: wave-private 4KB region; issue j = rows j*4..j*4+3 (1KB lane-linear)
    // LDS[row][g] = global[row][g^row] (g = 16B granule, 16/row) — verified pattern
    #define STAGE_A(s) do {                                                             \
        _Pragma("unroll")                                                               \
        for (int j = 0; j < 4; ++j) {                                                   \
            int rloc = j * 4 + (l >> 4);                                                \
            int gs = (l & 15) ^ rloc;                                                   \
            gload_lds16(src + (size_t)(rowbase + rloc) * CC + kbase0 + (s) * 64 + gs * 4, \
                        smem + ((s) & 1) * 32768 + w * 4096 + j * 1024);                \
        }                                                                               \
    } while (0)

    f32x4 accA[4], accV[4];
    #pragma unroll
    for (int i = 0; i < 4; i++) { accA[i] = (f32x4){0.f,0.f,0.f,0.f}; accV[i] = (f32x4){0.f,0.f,0.f,0.f}; }

    STAGE_A(0);

    if (kv) {
        #pragma unroll
        for (int s = 0; s < 8; ++s) {
            // B register loads FIRST (older than stage(s+1) in vmcnt order)
            bf16x8 bA[2][4], bV[2][4];
            #pragma unroll
            for (int nt = 0; nt < 4; nt++) {
                const __bf16* pa = wA + (size_t)(nt * 16 + lm) * CC + kbase0 + s * 64 + lq * 8;
                const __bf16* pv = wV + (size_t)(nt * 16 + lm) * CC + kbase0 + s * 64 + lq * 8;
                bA[0][nt] = *(const bf16x8*)(pa);
                bA[1][nt] = *(const bf16x8*)(pa + 32);
                bV[0][nt] = *(const bf16x8*)(pv);
                bV[1][nt] = *(const bf16x8*)(pv + 32);
            }
            if (s < 7) {
                STAGE_A(s + 1);
                asm volatile("s_waitcnt vmcnt(20)" ::: "memory");   // 16 B + 4 stage newer
            } else {
                asm volatile("s_waitcnt vmcnt(16)" ::: "memory");   // 16 B newer
            }
            const char* Ab = smem + (s & 1) * 32768 + w * 4096;
            #pragma unroll
            for (int ks = 0; ks < 2; ++ks) {
                int g0 = ks * 8 + lq * 2;
                float4 f0 = *(const float4*)(Ab + lm * 256 + ((g0)     ^ lm) * 16);
                float4 f1 = *(const float4*)(Ab + lm * 256 + ((g0 + 1) ^ lm) * 16);
                bf16x8 af = cvt8(f0, f1);
                #pragma unroll
                for (int nt = 0; nt < 4; nt++) {
                    accA[nt] = MFMA16(af, bA[ks][nt], accA[nt]);
                    accV[nt] = MFMA16(af, bV[ks][nt], accV[nt]);
                }
            }
        }
    } else {
        #pragma unroll
        for (int s = 0; s < 8; ++s) {
            bf16x8 bA[2][4];
            #pragma unroll
            for (int nt = 0; nt < 4; nt++) {
                const __bf16* pa = wA + (size_t)(nt * 16 + lm) * CC + kbase0 + s * 64 + lq * 8;
                bA[0][nt] = *(const bf16x8*)(pa);
                bA[1][nt] = *(const bf16x8*)(pa + 32);
            }
            if (s < 7) {
                STAGE_A(s + 1);
                asm volatile("s_waitcnt vmcnt(12)" ::: "memory");   // 8 B + 4 stage newer
            } else {
                asm volatile("s_waitcnt vmcnt(8)" ::: "memory");    // 8 B newer
            }
            const char* Ab = smem + (s & 1) * 32768 + w * 4096;
            #pragma unroll
            for (int ks = 0; ks < 2; ++ks) {
                int g0 = ks * 8 + lq * 2;
                float4 f0 = *(const float4*)(Ab + lm * 256 + ((g0)     ^ lm) * 16);
                float4 f1 = *(const float4*)(Ab + lm * 256 + ((g0 + 1) ^ lm) * 16);
                bf16x8 af = cvt8(f0, f1);
                #pragma unroll
                for (int nt = 0; nt < 4; nt++)
                    accA[nt] = MFMA16(af, bA[ks][nt], accA[nt]);
            }
        }
    }
    #undef STAGE_A

    // ---- k-half combine: kh=1 waves dump accs; kh=0 waves add + store ----
    __syncthreads();                            // all waves done reading A-LDS
    if (kh == 1) {
        char* dump = smem + rg * 8192;          // lane-interleaved: 16B x 64 lanes per quad
        #pragma unroll
        for (int g = 0; g < 4; ++g)
            *(f32x4*)(dump + (g * 64 + l) * 16) = accA[g];
        if (kv) {
            #pragma unroll
            for (int g = 0; g < 4; ++g)
                *(f32x4*)(dump + ((4 + g) * 64 + l) * 16) = accV[g];
        }
    }
    __syncthreads();
    if (kh == 0) {
        const char* dump = smem + rg * 8192;
        #pragma unroll
        for (int g = 0; g < 4; ++g)
            accA[g] += *(const f32x4*)(dump + (g * 64 + l) * 16);
        if (kv) {
            #pragma unroll
            for (int g = 0; g < 4; ++g)
                accV[g] += *(const f32x4*)(dump + ((4 + g) * 64 + l) * 16);
        }
        // epilogue q/k: D row m = lq*4+r (wave-local), col n = nt*16+lm  (verified)
        __bf16* dstA = kv ? kb : qb;
        #pragma unroll
        for (int nt = 0; nt < 4; nt++)
            #pragma unroll
            for (int r = 0; r < 4; r++)
                dstA[(size_t)(rowbase + lq * 4 + r) * HS + nt * 16 + lm] = (__bf16)accA[nt][r];
        // epilogue v: vt[b][d][s]; D rows are consecutive s -> 8B contiguous  (verified)
        if (kv) {
            int bb = row0 >> 12;
            int sbase = (row0 & 4095) + rg * 16 + lq * 4;
            #pragma unroll
            for (int nt = 0; nt < 4; nt++) {
                bf16x4 pk = { (__bf16)accV[nt][0], (__bf16)accV[nt][1],
                              (__bf16)accV[nt][2], (__bf16)accV[nt][3] };
                *(bf16x4*)(vt + ((size_t)bb * HS + nt * 16 + lm) * SS + sbase) = pk;
            }
        }
    }
}

// ---------------- flash attention (unchanged from round 8 — verified, at L2 roofline) --
__global__ __launch_bounds__(512, 1) void attn(const __bf16* __restrict__ qb,
                                               const __bf16* __restrict__ kb,
                                               const __bf16* __restrict__ vt,
                                               float* __restrict__ out) {
    extern __shared__ char smem[];              // 131072 B
    int tid = threadIdx.x, w = tid >> 6, l = tid & 63;
    int hi = l >> 5, ln = l & 31;
    int qg = w & 1, ss = w >> 1;

    int bid = blockIdx.x;
    int b = bid & 3, tb = bid >> 2;             // XCD (bid%8) -> fixed batch (b=bid&3)
    int t0 = tb * 64;

    const __bf16* qp = qb + ((size_t)(b * TT + t0 + qg * 32 + ln)) * HS + hi * 8;
    bf16x8 qf[4];
    qf[0] = *(const bf16x8*)(qp);
    qf[1] = *(const bf16x8*)(qp + 16);
    qf[2] = *(const bf16x8*)(qp + 32);
    qf[3] = *(const bf16x8*)(qp + 48);

    const __bf16* kbase = kb + (size_t)b * SS * HS;   // [4096][64]
    const __bf16* vbase = vt + (size_t)b * HS * SS;   // [64][4096]

    #define STAGE(t, p) do {                                                            \
        _Pragma("unroll")                                                               \
        for (int i = 0; i < 4; ++i) {                                                   \
            int idx = i * 512 + tid;                                                    \
            int sr = idx >> 3, g = idx & 7;                                             \
            gload_lds16(kbase + ((size_t)(t) * 256 + sr) * 64 + ((g ^ (sr & 7)) * 8),   \
                        smem + (p) * 65536 + idx * 16);                                 \
        }                                                                               \
        _Pragma("unroll")                                                               \
        for (int i = 0; i < 4; ++i) {                                                   \
            int idx = i * 512 + tid;                                                    \
            int dr = idx >> 5, g = idx & 31;                                            \
            gload_lds16(vbase + (size_t)dr * SS + (t) * 256 + ((g ^ (dr & 7)) * 8),     \
                        smem + (p) * 65536 + 32768 + idx * 16);                         \
        }                                                                               \
    } while (0)

    f32x16 oacc0, oacc1;
    #pragma unroll
    for (int i = 0; i < 16; i++) { oacc0[i] = 0.f; oacc1[i] = 0.f; }
    float lsum = 0.f;

    STAGE(0, 0);
    for (int t = 0; t < 16; ++t) {
        int p = t & 1;
        if (t < 15) {
            STAGE(t + 1, p ^ 1);
            asm volatile("s_waitcnt vmcnt(8)\ns_barrier" ::: "memory");
        } else {
            asm volatile("s_waitcnt vmcnt(0)\ns_barrier" ::: "memory");
        }
        const char* Kb = smem + p * 65536;
        const char* Vb = smem + p * 65536 + 32768;

        #pragma unroll
        for (int sg = 0; sg < 2; ++sg) {
            int srow = ss * 64 + sg * 32 + ln;
            bf16x8 ka[4];
            #pragma unroll
            for (int ks = 0; ks < 4; ++ks)
                ka[ks] = *(const bf16x8*)(Kb + srow * 128 + (((ks * 2 + hi) ^ (srow & 7)) * 16));

            f32x16 s;
            #pragma unroll
            for (int i = 0; i < 16; i++) s[i] = 0.f;
            s = MFMA32(ka[0], qf[0], s);
            s = MFMA32(ka[1], qf[1], s);
            s = MFMA32(ka[2], qf[2], s);
            s = MFMA32(ka[3], qf[3], s);

            float pv[16];
            #pragma unroll
            for (int i = 0; i < 16; i++) pv[i] = __builtin_amdgcn_exp2f(s[i]);
            float l0 = (pv[0] + pv[1]) + (pv[2] + pv[3]);
            float l1 = (pv[4] + pv[5]) + (pv[6] + pv[7]);
            float l2 = (pv[8] + pv[9]) + (pv[10] + pv[11]);
            float l3 = (pv[12] + pv[13]) + (pv[14] + pv[15]);
            lsum += (l0 + l1) + (l2 + l3);

            int d01 = pkbf(pv[0],  pv[1]),  d23 = pkbf(pv[2],  pv[3]);
            int d45 = pkbf(pv[4],  pv[5]),  d67 = pkbf(pv[6],  pv[7]);
            int e01 = pkbf(pv[8],  pv[9]),  e23 = pkbf(pv[10], pv[11]);
            int e45 = pkbf(pv[12], pv[13]), e67 = pkbf(pv[14], pv[15]);
            asm("v_permlane32_swap_b32 %0, %1" : "+v"(d01), "+v"(d45));
            asm("v_permlane32_swap_b32 %0, %1" : "+v"(d23), "+v"(d67));
            asm("v_permlane32_swap_b32 %0, %1" : "+v"(e01), "+v"(e45));
            asm("v_permlane32_swap_b32 %0, %1" : "+v"(e23), "+v"(e67));
            union F { int i[4]; bf16x8 v; } f0, f1;
            f0.i[0] = d01; f0.i[1] = d23; f0.i[2] = d45; f0.i[3] = d67;
            f1.i[0] = e01; f1.i[1] = e23; f1.i[2] = e45; f1.i[3] = e67;

            int ksp = ss * 4 + sg * 2;
            #pragma unroll
            for (int dg = 0; dg < 2; ++dg) {
                int d = dg * 32 + ln;
                bf16x8 va0 = *(const bf16x8*)(Vb + d * 512 + ((((ksp)     * 2 + hi) ^ (d & 7)) * 16));
                bf16x8 va1 = *(const bf16x8*)(Vb + d * 512 + ((((ksp + 1) * 2 + hi) ^ (d & 7)) * 16));
                if (dg == 0) { oacc0 = MFMA32(va0, f0.v, oacc0); oacc0 = MFMA32(va1, f1.v, oacc0); }
                else         { oacc1 = MFMA32(va0, f0.v, oacc1); oacc1 = MFMA32(va1, f1.v, oacc1); }
            }
        }
        asm volatile("s_waitcnt lgkmcnt(0)\ns_barrier" ::: "memory");
    }
    #undef STAGE

    lsum += __shfl_xor(lsum, 32, 64);

    float* accC = (float*)smem;                      // [16][64][20]
    float* lsC  = (float*)(smem + 102400);           // [8][32], slot = qg*4+ss
    union O { f32x16 v; f32x4 q[4]; } o0, o1;
    o0.v = oacc0; o1.v = oacc1;
    {
        int b0 = ((qg * 4 + ss) * 2 + 0) * 1280 + l * 20;
        int b1 = ((qg * 4 + ss) * 2 + 1) * 1280 + l * 20;
        #pragma unroll
        for (int g = 0; g < 4; ++g) {
            *(f32x4*)&accC[b0 + g * 4] = o0.q[g];
            *(f32x4*)&accC[b1 + g * 4] = o1.q[g];
        }
        if (l < 32) lsC[(qg * 4 + ss) * 32 + l] = lsum;
    }
    __syncthreads();

    {
        int q = tid >> 3, c8 = tid & 7;
        int qg2 = q >> 5, ln2 = q & 31;
        float ls = 0.f;
        #pragma unroll
        for (int s2 = 0; s2 < 4; ++s2) ls += lsC[(qg2 * 4 + s2) * 32 + ln2];
        float inv = 1.0f / ls;
        float vout[8];
        #pragma unroll
        for (int j = 0; j < 8; ++j) {
            int d = c8 * 8 + j;
            int hi2 = (d >> 2) & 1, dg = d >> 5;
            int r = (((d & 31) >> 3) << 2) | (d & 3);
            float sum = 0.f;
            #pragma unroll
            for (int s2 = 0; s2 < 4; ++s2)
                sum += accC[((qg2 * 4 + s2) * 2 + dg) * 1280 + (hi2 * 32 + ln2) * 20 + r];
            vout[j] = sum * inv;
        }
        float* orow = out + (size_t)(b * TT + t0 + q) * HS + c8 * 8;
        *(f32x4*)(orow)     = *(f32x4*)&vout[0];
        *(f32x4*)(orow + 4) = *(f32x4*)&vout[4];
    }
}

// ---------------- launcher --------------------------------------------------------------
extern "C" void kernel_launch(void* const* d_in, const int* in_sizes, int n_in,
                              void* d_out, int out_size, void* d_ws, size_t ws_size,
                              hipStream_t stream) {
    (void)in_sizes; (void)n_in; (void)out_size; (void)ws_size;
    const float* x   = (const float*)d_in[0];
    const float* enc = (const float*)d_in[1];
    const float* Wq  = (const float*)d_in[2];
    const float* Wk  = (const float*)d_in[3];
    const float* Wv  = (const float*)d_in[4];
    float* out = (float*)d_out;

    char* ws = (char*)d_ws;
    __bf16* wtb  = (__bf16*)ws;                            // 393216 B
    __bf16* qbuf = (__bf16*)(ws + 393216);                 // 2 MB
    __bf16* kbuf = (__bf16*)(ws + 393216 + 2097152);       // 2 MB
    __bf16* vbuf = (__bf16*)(ws + 393216 + 2 * 2097152);   // 2 MB

    hipLaunchKernelGGL(prep_wt,  dim3(768), dim3(256), 0,      stream, Wq, Wk, Wv, wtb);
    hipLaunchKernelGGL(proj_qkv, dim3(512), dim3(512), 65536,  stream, x, enc, wtb, qbuf, kbuf, vbuf);
    hipLaunchKernelGGL(attn,     dim3(256), dim3(512), 131072, stream, qbuf, kbuf, vbuf, out);
}

// Round 12
// 72.026 us; speedup vs baseline: 1.5247x; 1.5247x over previous
//
#include <hip/hip_runtime.h>
#include <hip/hip_bf16.h>

#define TT 4096
#define SS 4096
#define CC 1024
#define HS 64

typedef __bf16 bf16x8 __attribute__((ext_vector_type(8)));
typedef __bf16 bf16x4 __attribute__((ext_vector_type(4)));
typedef float  f32x4  __attribute__((ext_vector_type(4)));
typedef float  f32x16 __attribute__((ext_vector_type(16)));

#define MFMA16(A,B,C) __builtin_amdgcn_mfma_f32_16x16x32_bf16((A),(B),(C),0,0,0)
#define MFMA32(A,B,C) __builtin_amdgcn_mfma_f32_32x32x16_bf16((A),(B),(C),0,0,0)

__device__ __forceinline__ int pkbf(float a, float b) {
    union { struct { __bf16 lo, hi; } h; int i; } u;
    u.h.lo = (__bf16)a; u.h.hi = (__bf16)b;
    return u.i;
}

__device__ __forceinline__ bf16x8 cvt8(float4 f0, float4 f1) {
    bf16x8 a;
    a[0] = (__bf16)f0.x; a[1] = (__bf16)f0.y; a[2] = (__bf16)f0.z; a[3] = (__bf16)f0.w;
    a[4] = (__bf16)f1.x; a[5] = (__bf16)f1.y; a[6] = (__bf16)f1.z; a[7] = (__bf16)f1.w;
    return a;
}

// fire-and-forget global->LDS, 16B per lane; LDS dest = wave-uniform base + lane*16
__device__ __forceinline__ void gload_lds16(const void* g, char* l) {
    __builtin_amdgcn_global_load_lds(
        (const __attribute__((address_space(1))) void*)g,
        (__attribute__((address_space(3))) void*)l, 16, 0, 0);
}

// ---------------- prep: W[1024][64] fp32 -> WT[64][1024] bf16 --------------------------
__global__ __launch_bounds__(256) void prep_wt(const float* __restrict__ Wq,
                                               const float* __restrict__ Wk,
                                               const float* __restrict__ Wv,
                                               __bf16* __restrict__ wt) {
    int idx = blockIdx.x * 256 + threadIdx.x;   // 3*65536 total
    int mat = idx >> 16;
    int e   = idx & 65535;
    int d   = e >> 10;
    int kk  = e & 1023;
    const float* W = (mat == 0) ? Wq : (mat == 1 ? Wk : Wv);
    float v = W[kk * HS + d];
    if (mat == 0) v *= 0.125f * 1.44269504088896340736f;
    wt[idx] = (__bf16)v;                        // wt[mat][d][kk]
}

// ---------------- QKV projection: full-row contiguous staging, B in registers ----------
// 256 blocks x 512 thr (1 block/CU). bid&1: 0 -> q from x, 1 -> k+v from enc.
// Block = 128 rows = 8 groups of 16. Per phase: stage group g+1 (64KB CONTIGUOUS,
// 64 x 1KB gload_lds issues) -> vmcnt(8)/wave + barrier -> compute 32 MFMA16 from
// LDS A + register B (loaded once, 32 x bf16x8 = 128 VGPR, static idx) -> store
// 16x64 tile -> lgkmcnt(0) + barrier. No k-split, no combine, 2 barriers/phase.
// kv: 8 waves = 4xWk-cols + 4xWv-cols. q: waves 0-3 compute, 4-7 stage-only.
// Swizzle (involution, within 256B subchunks of a row): lds_g = (g&~15)|((g^row)&15),
// applied to the GLOBAL source (lds dest lane-linear) and same on read (rule #21).
__global__ __launch_bounds__(512, 2) void proj_qkv(const float* __restrict__ x,
                                                   const float* __restrict__ enc,
                                                   const __bf16* __restrict__ wt,
                                                   __bf16* __restrict__ qb,
                                                   __bf16* __restrict__ kb,
                                                   __bf16* __restrict__ vt) {
    extern __shared__ char smem[];              // 131072: A dbuf 2 x 64KB
    int tid = threadIdx.x;
    int w = tid >> 6, l = tid & 63, lq = l >> 4, lm = l & 15;
    int kv   = blockIdx.x & 1;
    int row0 = (blockIdx.x >> 1) * 128;
    const float* src = kv ? enc : x;

    int  cg   = w & 3;                          // column group (16 cols)
    bool comp = kv ? true : (w < 4);            // q-blocks: waves 4-7 stage-only
    int  mat  = kv ? ((w < 4) ? 1 : 2) : 0;     // wt matrix index

    // ---- B resident in registers: wave's 16 cols x full K (or nothing if stage-only) --
    bf16x8 B[32];
    if (comp) {
        const __bf16* bp = wt + (size_t)mat * HS * CC + (size_t)(cg * 16 + lm) * CC + lq * 8;
        #pragma unroll
        for (int ks = 0; ks < 32; ++ks)
            B[ks] = *(const bf16x8*)(bp + ks * 32);
    }

    // stage group g into buffer g&1: issue i = w*8+ii covers row i>>2, quarter i&3 (1KB)
    // lane l: lds granule gl = q4*64+l ; global granule = (gl&~15)|((gl^row)&15)
    #define STAGE(g) do {                                                               \
        _Pragma("unroll")                                                               \
        for (int ii = 0; ii < 8; ++ii) {                                                \
            int i  = w * 8 + ii;                                                        \
            int r  = i >> 2;                                                            \
            int q4 = i & 3;                                                             \
            int gl = q4 * 64 + l;                                                       \
            int gs = (gl & ~15) | ((gl ^ r) & 15);                                      \
            gload_lds16(src + (size_t)(row0 + (g) * 16 + r) * CC + gs * 4,              \
                        smem + ((g) & 1) * 65536 + r * 4096 + q4 * 1024);               \
        }                                                                               \
    } while (0)

    STAGE(0);
    #pragma unroll
    for (int p = 0; p < 8; ++p) {
        if (p < 7) {
            STAGE(p + 1);
            asm volatile("s_waitcnt vmcnt(8)\ns_barrier" ::: "memory");
        } else {
            asm volatile("s_waitcnt vmcnt(0)\ns_barrier" ::: "memory");
        }
        if (comp) {
            const char* Ab = smem + (p & 1) * 65536 + (size_t)lm * 4096;
            f32x4 acc = (f32x4){0.f, 0.f, 0.f, 0.f};
            #pragma unroll
            for (int ks = 0; ks < 32; ++ks) {
                int g0 = ks * 8 + lq * 2;
                int b0 = (g0 & ~15) | ((g0 ^ lm) & 15);
                int g1 = g0 + 1;
                int b1 = (g1 & ~15) | ((g1 ^ lm) & 15);
                float4 f0 = *(const float4*)(Ab + b0 * 16);
                float4 f1 = *(const float4*)(Ab + b1 * 16);
                acc = MFMA16(cvt8(f0, f1), B[ks], acc);
            }
            // ---- store this group's 16x16 tile (D: row m=lq*4+r, col n=lm) ----
            int grow = row0 + p * 16;
            if (mat < 2) {                       // q or k: row-major [row][64]
                __bf16* dst = kv ? kb : qb;
                #pragma unroll
                for (int r = 0; r < 4; ++r)
                    dst[(size_t)(grow + lq * 4 + r) * HS + cg * 16 + lm] = (__bf16)acc[r];
            } else {                             // v transposed: vt[b][d][s]
                int bb = row0 >> 12;
                int sb = (grow & 4095) + lq * 4;
                bf16x4 pk = { (__bf16)acc[0], (__bf16)acc[1], (__bf16)acc[2], (__bf16)acc[3] };
                *(bf16x4*)(vt + ((size_t)bb * HS + cg * 16 + lm) * SS + sb) = pk;
            }
        }
        asm volatile("s_waitcnt lgkmcnt(0)\ns_barrier" ::: "memory");
    }
    #undef STAGE
}

// ---------------- flash attention (unchanged from round 8 — verified, at L2 roofline) --
__global__ __launch_bounds__(512, 1) void attn(const __bf16* __restrict__ qb,
                                               const __bf16* __restrict__ kb,
                                               const __bf16* __restrict__ vt,
                                               float* __restrict__ out) {
    extern __shared__ char smem[];              // 131072 B
    int tid = threadIdx.x, w = tid >> 6, l = tid & 63;
    int hi = l >> 5, ln = l & 31;
    int qg = w & 1, ss = w >> 1;

    int bid = blockIdx.x;
    int b = bid & 3, tb = bid >> 2;             // XCD (bid%8) -> fixed batch (b=bid&3)
    int t0 = tb * 64;

    const __bf16* qp = qb + ((size_t)(b * TT + t0 + qg * 32 + ln)) * HS + hi * 8;
    bf16x8 qf[4];
    qf[0] = *(const bf16x8*)(qp);
    qf[1] = *(const bf16x8*)(qp + 16);
    qf[2] = *(const bf16x8*)(qp + 32);
    qf[3] = *(const bf16x8*)(qp + 48);

    const __bf16* kbase = kb + (size_t)b * SS * HS;   // [4096][64]
    const __bf16* vbase = vt + (size_t)b * HS * SS;   // [64][4096]

    #define STAGE(t, p) do {                                                            \
        _Pragma("unroll")                                                               \
        for (int i = 0; i < 4; ++i) {                                                   \
            int idx = i * 512 + tid;                                                    \
            int sr = idx >> 3, g = idx & 7;                                             \
            gload_lds16(kbase + ((size_t)(t) * 256 + sr) * 64 + ((g ^ (sr & 7)) * 8),   \
                        smem + (p) * 65536 + idx * 16);                                 \
        }                                                                               \
        _Pragma("unroll")                                                               \
        for (int i = 0; i < 4; ++i) {                                                   \
            int idx = i * 512 + tid;                                                    \
            int dr = idx >> 5, g = idx & 31;                                            \
            gload_lds16(vbase + (size_t)dr * SS + (t) * 256 + ((g ^ (dr & 7)) * 8),     \
                        smem + (p) * 65536 + 32768 + idx * 16);                         \
        }                                                                               \
    } while (0)

    f32x16 oacc0, oacc1;
    #pragma unroll
    for (int i = 0; i < 16; i++) { oacc0[i] = 0.f; oacc1[i] = 0.f; }
    float lsum = 0.f;

    STAGE(0, 0);
    for (int t = 0; t < 16; ++t) {
        int p = t & 1;
        if (t < 15) {
            STAGE(t + 1, p ^ 1);
            asm volatile("s_waitcnt vmcnt(8)\ns_barrier" ::: "memory");
        } else {
            asm volatile("s_waitcnt vmcnt(0)\ns_barrier" ::: "memory");
        }
        const char* Kb = smem + p * 65536;
        const char* Vb = smem + p * 65536 + 32768;

        #pragma unroll
        for (int sg = 0; sg < 2; ++sg) {
            int srow = ss * 64 + sg * 32 + ln;
            bf16x8 ka[4];
            #pragma unroll
            for (int ks = 0; ks < 4; ++ks)
                ka[ks] = *(const bf16x8*)(Kb + srow * 128 + (((ks * 2 + hi) ^ (srow & 7)) * 16));

            f32x16 s;
            #pragma unroll
            for (int i = 0; i < 16; i++) s[i] = 0.f;
            s = MFMA32(ka[0], qf[0], s);
            s = MFMA32(ka[1], qf[1], s);
            s = MFMA32(ka[2], qf[2], s);
            s = MFMA32(ka[3], qf[3], s);

            float pv[16];
            #pragma unroll
            for (int i = 0; i < 16; i++) pv[i] = __builtin_amdgcn_exp2f(s[i]);
            float l0 = (pv[0] + pv[1]) + (pv[2] + pv[3]);
            float l1 = (pv[4] + pv[5]) + (pv[6] + pv[7]);
            float l2 = (pv[8] + pv[9]) + (pv[10] + pv[11]);
            float l3 = (pv[12] + pv[13]) + (pv[14] + pv[15]);
            lsum += (l0 + l1) + (l2 + l3);

            int d01 = pkbf(pv[0],  pv[1]),  d23 = pkbf(pv[2],  pv[3]);
            int d45 = pkbf(pv[4],  pv[5]),  d67 = pkbf(pv[6],  pv[7]);
            int e01 = pkbf(pv[8],  pv[9]),  e23 = pkbf(pv[10], pv[11]);
            int e45 = pkbf(pv[12], pv[13]), e67 = pkbf(pv[14], pv[15]);
            asm("v_permlane32_swap_b32 %0, %1" : "+v"(d01), "+v"(d45));
            asm("v_permlane32_swap_b32 %0, %1" : "+v"(d23), "+v"(d67));
            asm("v_permlane32_swap_b32 %0, %1" : "+v"(e01), "+v"(e45));
            asm("v_permlane32_swap_b32 %0, %1" : "+v"(e23), "+v"(e67));
            union F { int i[4]; bf16x8 v; } f0, f1;
            f0.i[0] = d01; f0.i[1] = d23; f0.i[2] = d45; f0.i[3] = d67;
            f1.i[0] = e01; f1.i[1] = e23; f1.i[2] = e45; f1.i[3] = e67;

            int ksp = ss * 4 + sg * 2;
            #pragma unroll
            for (int dg = 0; dg < 2; ++dg) {
                int d = dg * 32 + ln;
                bf16x8 va0 = *(const bf16x8*)(Vb + d * 512 + ((((ksp)     * 2 + hi) ^ (d & 7)) * 16));
                bf16x8 va1 = *(const bf16x8*)(Vb + d * 512 + ((((ksp + 1) * 2 + hi) ^ (d & 7)) * 16));
                if (dg == 0) { oacc0 = MFMA32(va0, f0.v, oacc0); oacc0 = MFMA32(va1, f1.v, oacc0); }
                else         { oacc1 = MFMA32(va0, f0.v, oacc1); oacc1 = MFMA32(va1, f1.v, oacc1); }
            }
        }
        asm volatile("s_waitcnt lgkmcnt(0)\ns_barrier" ::: "memory");
    }
    #undef STAGE

    lsum += __shfl_xor(lsum, 32, 64);

    float* accC = (float*)smem;                      // [16][64][20]
    float* lsC  = (float*)(smem + 102400);           // [8][32], slot = qg*4+ss
    union O { f32x16 v; f32x4 q[4]; } o0, o1;
    o0.v = oacc0; o1.v = oacc1;
    {
        int b0 = ((qg * 4 + ss) * 2 + 0) * 1280 + l * 20;
        int b1 = ((qg * 4 + ss) * 2 + 1) * 1280 + l * 20;
        #pragma unroll
        for (int g = 0; g < 4; ++g) {
            *(f32x4*)&accC[b0 + g * 4] = o0.q[g];
            *(f32x4*)&accC[b1 + g * 4] = o1.q[g];
        }
        if (l < 32) lsC[(qg * 4 + ss) * 32 + l] = lsum;
    }
    __syncthreads();

    {
        int q = tid >> 3, c8 = tid & 7;
        int qg2 = q >> 5, ln2 = q & 31;
        float ls = 0.f;
        #pragma unroll
        for (int s2 = 0; s2 < 4; ++s2) ls += lsC[(qg2 * 4 + s2) * 32 + ln2];
        float inv = 1.0f / ls;
        float vout[8];
        #pragma unroll
        for (int j = 0; j < 8; ++j) {
            int d = c8 * 8 + j;
            int hi2 = (d >> 2) & 1, dg = d >> 5;
            int r = (((d & 31) >> 3) << 2) | (d & 3);
            float sum = 0.f;
            #pragma unroll
            for (int s2 = 0; s2 < 4; ++s2)
                sum += accC[((qg2 * 4 + s2) * 2 + dg) * 1280 + (hi2 * 32 + ln2) * 20 + r];
            vout[j] = sum * inv;
        }
        float* orow = out + (size_t)(b * TT + t0 + q) * HS + c8 * 8;
        *(f32x4*)(orow)     = *(f32x4*)&vout[0];
        *(f32x4*)(orow + 4) = *(f32x4*)&vout[4];
    }
}

// ---------------- launcher --------------------------------------------------------------
extern "C" void kernel_launch(void* const* d_in, const int* in_sizes, int n_in,
                              void* d_out, int out_size, void* d_ws, size_t ws_size,
                              hipStream_t stream) {
    (void)in_sizes; (void)n_in; (void)out_size; (void)ws_size;
    const float* x   = (const float*)d_in[0];
    const float* enc = (const float*)d_in[1];
    const float* Wq  = (const float*)d_in[2];
    const float* Wk  = (const float*)d_in[3];
    const float* Wv  = (const float*)d_in[4];
    float* out = (float*)d_out;

    char* ws = (char*)d_ws;
    __bf16* wtb  = (__bf16*)ws;                            // 393216 B
    __bf16* qbuf = (__bf16*)(ws + 393216);                 // 2 MB
    __bf16* kbuf = (__bf16*)(ws + 393216 + 2097152);       // 2 MB
    __bf16* vbuf = (__bf16*)(ws + 393216 + 2 * 2097152);   // 2 MB

    hipLaunchKernelGGL(prep_wt,  dim3(768), dim3(256), 0,      stream, Wq, Wk, Wv, wtb);
    hipLaunchKernelGGL(proj_qkv, dim3(256), dim3(512), 131072, stream, x, enc, wtb, qbuf, kbuf, vbuf);
    hipLaunchKernelGGL(attn,     dim3(256), dim3(512), 131072, stream, qbuf, kbuf, vbuf, out);
}

// Round 13
// 70.600 us; speedup vs baseline: 1.5555x; 1.0202x over previous
//
#include <hip/hip_runtime.h>
#include <hip/hip_bf16.h>

#define TT 4096
#define SS 4096
#define CC 1024
#define HS 64

typedef __bf16 bf16x8 __attribute__((ext_vector_type(8)));
typedef __bf16 bf16x4 __attribute__((ext_vector_type(4)));
typedef float  f32x4  __attribute__((ext_vector_type(4)));
typedef float  f32x16 __attribute__((ext_vector_type(16)));

#define MFMA16(A,B,C) __builtin_amdgcn_mfma_f32_16x16x32_bf16((A),(B),(C),0,0,0)
#define MFMA32(A,B,C) __builtin_amdgcn_mfma_f32_32x32x16_bf16((A),(B),(C),0,0,0)

__device__ __forceinline__ int pkbf(float a, float b) {
    union { struct { __bf16 lo, hi; } h; int i; } u;
    u.h.lo = (__bf16)a; u.h.hi = (__bf16)b;
    return u.i;
}

__device__ __forceinline__ bf16x8 cvt8(float4 f0, float4 f1) {
    bf16x8 a;
    a[0] = (__bf16)f0.x; a[1] = (__bf16)f0.y; a[2] = (__bf16)f0.z; a[3] = (__bf16)f0.w;
    a[4] = (__bf16)f1.x; a[5] = (__bf16)f1.y; a[6] = (__bf16)f1.z; a[7] = (__bf16)f1.w;
    return a;
}

// fire-and-forget global->LDS, 16B per lane; LDS dest = wave-uniform base + lane*16
__device__ __forceinline__ void gload_lds16(const void* g, char* l) {
    __builtin_amdgcn_global_load_lds(
        (const __attribute__((address_space(1))) void*)g,
        (__attribute__((address_space(3))) void*)l, 16, 0, 0);
}
// non-temporal variant (cpol NT bit): single-use streaming source, evict-first
__device__ __forceinline__ void gload_lds16_nt(const void* g, char* l) {
    __builtin_amdgcn_global_load_lds(
        (const __attribute__((address_space(1))) void*)g,
        (__attribute__((address_space(3))) void*)l, 16, 0, 2);
}

// ---------------- prep: W[1024][64] fp32 -> WT[64][1024] bf16 --------------------------
__global__ __launch_bounds__(256) void prep_wt(const float* __restrict__ Wq,
                                               const float* __restrict__ Wk,
                                               const float* __restrict__ Wv,
                                               __bf16* __restrict__ wt) {
    int idx = blockIdx.x * 256 + threadIdx.x;   // 3*65536 total
    int mat = idx >> 16;
    int e   = idx & 65535;
    int d   = e >> 10;
    int kk  = e & 1023;
    const float* W = (mat == 0) ? Wq : (mat == 1 ? Wk : Wv);
    float v = W[kk * HS + d];
    if (mat == 0) v *= 0.125f * 1.44269504088896340736f;
    wt[idx] = (__bf16)v;                        // wt[mat][d][kk]
}

// ---------------- QKV projection (R9 structure, best measured) + NT + XCD-mix ----------
// 256 blocks x 512 thr, 1 block/CU. kv = (bid>>3)&1 so BOTH input streams (x, enc)
// flow through ALL 8 XCDs (bid&1 confined each stream to 4 XCDs' L2/fabric).
// Block = 128 rows, wave w owns 16. 16 K-steps of 64. A triple-buffered (3x32KB,
// depth-2 prefetch) staged with NT policy (single-use stream); B double-buffered
// (2x16KB, default policy - reused). Counted vmcnt + 2 barriers per step.
__global__ __launch_bounds__(512, 1) void proj_qkv(const float* __restrict__ x,
                                                   const float* __restrict__ enc,
                                                   const __bf16* __restrict__ wt,
                                                   __bf16* __restrict__ qb,
                                                   __bf16* __restrict__ kb,
                                                   __bf16* __restrict__ vt) {
    extern __shared__ char smem[];              // 131072: A 3x32K @0 ; B 2x16K @98304
    int tid = threadIdx.x;
    int w = tid >> 6, l = tid & 63, lq = l >> 4, lm = l & 15;
    int bid = blockIdx.x;
    int kv  = (bid >> 3) & 1;                   // XCD-mix: both streams on all XCDs
    int idx = ((bid >> 4) << 3) | (bid & 7);    // [0,128) per stream, bijective
    int row0 = idx * 128;
    int rowbase = row0 + w * 16;
    const float*  src   = kv ? enc : x;
    const __bf16* wbase = wt + (kv ? HS * CC : 0);
    const __bf16* wvb   = wt + 2 * HS * CC;

    // A-stage (NT): wave w stages its own 16 rows into buffer k%3; issue j = 4 rows
    // LDS[row][g] = global[row][g^row] (g = 16B granule, 16/row) — verified pattern
    #define STAGE_A(k) do {                                                             \
        _Pragma("unroll")                                                               \
        for (int j = 0; j < 4; ++j) {                                                   \
            int rloc = j * 4 + (l >> 4);                                                \
            int gs = (l & 15) ^ rloc;                                                   \
            gload_lds16_nt(src + (size_t)(rowbase + rloc) * CC + (k) * 64 + gs * 4,     \
                           smem + ((k) % 3) * 32768 + w * 4096 + j * 1024);             \
        }                                                                               \
    } while (0)

    // B-stage: one issue per mat; wave w stages rows w*8..w*8+7 of the 64-row wt slice
    // LDS[row][g] = global[row][g^(row&7)] (g = 16B granule, 8/row)
    #define STAGE_B(k, mptr, moff) do {                                                 \
        int gs = (l & 7) ^ (l >> 3);                                                    \
        gload_lds16(mptr + (size_t)(w * 8 + (l >> 3)) * CC + (k) * 64 + gs * 8,         \
                    smem + 98304 + ((k) & 1) * 16384 + (moff) + w * 1024);              \
    } while (0)

    f32x4 accA[4], accV[4];
    #pragma unroll
    for (int i = 0; i < 4; i++) { accA[i] = (f32x4){0.f,0.f,0.f,0.f}; accV[i] = (f32x4){0.f,0.f,0.f,0.f}; }

    if (kv) {
        // prologue: B(0)[2] A(0)[4] A(1)[4] -> 10 outstanding
        STAGE_B(0, wbase, 0); STAGE_B(0, wvb, 8192);
        STAGE_A(0); STAGE_A(1);
        #pragma unroll
        for (int k = 0; k < 16; ++k) {
            if (k < 15) { STAGE_B(k + 1, wbase, 0); STAGE_B(k + 1, wvb, 8192); }
            if (k < 14) STAGE_A(k + 2);
            // counted waits: stage(k) landed; k+1 (and A k+2) stay in flight
            if (k < 14)       asm volatile("s_waitcnt vmcnt(10)\ns_barrier" ::: "memory");
            else if (k == 14) asm volatile("s_waitcnt vmcnt(6)\ns_barrier" ::: "memory");
            else              asm volatile("s_waitcnt vmcnt(0)\ns_barrier" ::: "memory");

            const char* Ab = smem + (k % 3) * 32768 + w * 4096;
            const char* Bb = smem + 98304 + (k & 1) * 16384;
            #pragma unroll
            for (int ks = 0; ks < 2; ++ks) {
                int g0 = ks * 8 + lq * 2;
                float4 f0 = *(const float4*)(Ab + lm * 256 + ((g0)     ^ lm) * 16);
                float4 f1 = *(const float4*)(Ab + lm * 256 + ((g0 + 1) ^ lm) * 16);
                bf16x8 af = cvt8(f0, f1);
                int bg = ((ks * 4 + lq) ^ (lm & 7)) * 16;
                #pragma unroll
                for (int nt = 0; nt < 4; nt++) {
                    bf16x8 bA = *(const bf16x8*)(Bb + (nt * 16 + lm) * 128 + bg);
                    bf16x8 bV = *(const bf16x8*)(Bb + 8192 + (nt * 16 + lm) * 128 + bg);
                    accA[nt] = MFMA16(af, bA, accA[nt]);
                    accV[nt] = MFMA16(af, bV, accV[nt]);
                }
            }
            asm volatile("s_waitcnt lgkmcnt(0)\ns_barrier" ::: "memory");
        }
    } else {
        // prologue: B(0)[1] A(0)[4] A(1)[4] -> 9 outstanding
        STAGE_B(0, wbase, 0);
        STAGE_A(0); STAGE_A(1);
        #pragma unroll
        for (int k = 0; k < 16; ++k) {
            if (k < 15) STAGE_B(k + 1, wbase, 0);
            if (k < 14) STAGE_A(k + 2);
            if (k < 14)       asm volatile("s_waitcnt vmcnt(9)\ns_barrier" ::: "memory");
            else if (k == 14) asm volatile("s_waitcnt vmcnt(5)\ns_barrier" ::: "memory");
            else              asm volatile("s_waitcnt vmcnt(0)\ns_barrier" ::: "memory");

            const char* Ab = smem + (k % 3) * 32768 + w * 4096;
            const char* Bb = smem + 98304 + (k & 1) * 16384;
            #pragma unroll
            for (int ks = 0; ks < 2; ++ks) {
                int g0 = ks * 8 + lq * 2;
                float4 f0 = *(const float4*)(Ab + lm * 256 + ((g0)     ^ lm) * 16);
                float4 f1 = *(const float4*)(Ab + lm * 256 + ((g0 + 1) ^ lm) * 16);
                bf16x8 af = cvt8(f0, f1);
                int bg = ((ks * 4 + lq) ^ (lm & 7)) * 16;
                #pragma unroll
                for (int nt = 0; nt < 4; nt++) {
                    bf16x8 bA = *(const bf16x8*)(Bb + (nt * 16 + lm) * 128 + bg);
                    accA[nt] = MFMA16(af, bA, accA[nt]);
                }
            }
            asm volatile("s_waitcnt lgkmcnt(0)\ns_barrier" ::: "memory");
        }
    }
    #undef STAGE_A
    #undef STAGE_B

    // ---- epilogue q/k: D row m = lq*4+r (wave-local), col n = nt*16+lm ----
    {
        __bf16* dstA = kv ? kb : qb;
        #pragma unroll
        for (int nt = 0; nt < 4; nt++)
            #pragma unroll
            for (int r = 0; r < 4; r++)
                dstA[(size_t)(rowbase + lq * 4 + r) * HS + nt * 16 + lm] = (__bf16)accA[nt][r];
    }
    // ---- epilogue v: vt[b][d][s]; D rows are consecutive s -> 8B contiguous ----
    if (kv) {
        int bb = row0 >> 12;
        int sbase = (row0 & 4095) + w * 16 + lq * 4;
        #pragma unroll
        for (int nt = 0; nt < 4; nt++) {
            bf16x4 pk = { (__bf16)accV[nt][0], (__bf16)accV[nt][1],
                          (__bf16)accV[nt][2], (__bf16)accV[nt][3] };
            *(bf16x4*)(vt + ((size_t)bb * HS + nt * 16 + lm) * SS + sbase) = pk;
        }
    }
}

// ---------------- flash attention (unchanged from round 8 — verified, at L2 roofline) --
__global__ __launch_bounds__(512, 1) void attn(const __bf16* __restrict__ qb,
                                               const __bf16* __restrict__ kb,
                                               const __bf16* __restrict__ vt,
                                               float* __restrict__ out) {
    extern __shared__ char smem[];              // 131072 B
    int tid = threadIdx.x, w = tid >> 6, l = tid & 63;
    int hi = l >> 5, ln = l & 31;
    int qg = w & 1, ss = w >> 1;

    int bid = blockIdx.x;
    int b = bid & 3, tb = bid >> 2;             // XCD (bid%8) -> fixed batch (b=bid&3)
    int t0 = tb * 64;

    const __bf16* qp = qb + ((size_t)(b * TT + t0 + qg * 32 + ln)) * HS + hi * 8;
    bf16x8 qf[4];
    qf[0] = *(const bf16x8*)(qp);
    qf[1] = *(const bf16x8*)(qp + 16);
    qf[2] = *(const bf16x8*)(qp + 32);
    qf[3] = *(const bf16x8*)(qp + 48);

    const __bf16* kbase = kb + (size_t)b * SS * HS;   // [4096][64]
    const __bf16* vbase = vt + (size_t)b * HS * SS;   // [64][4096]

    #define STAGE(t, p) do {                                                            \
        _Pragma("unroll")                                                               \
        for (int i = 0; i < 4; ++i) {                                                   \
            int idx = i * 512 + tid;                                                    \
            int sr = idx >> 3, g = idx & 7;                                             \
            gload_lds16(kbase + ((size_t)(t) * 256 + sr) * 64 + ((g ^ (sr & 7)) * 8),   \
                        smem + (p) * 65536 + idx * 16);                                 \
        }                                                                               \
        _Pragma("unroll")                                                               \
        for (int i = 0; i < 4; ++i) {                                                   \
            int idx = i * 512 + tid;                                                    \
            int dr = idx >> 5, g = idx & 31;                                            \
            gload_lds16(vbase + (size_t)dr * SS + (t) * 256 + ((g ^ (dr & 7)) * 8),     \
                        smem + (p) * 65536 + 32768 + idx * 16);                         \
        }                                                                               \
    } while (0)

    f32x16 oacc0, oacc1;
    #pragma unroll
    for (int i = 0; i < 16; i++) { oacc0[i] = 0.f; oacc1[i] = 0.f; }
    float lsum = 0.f;

    STAGE(0, 0);
    for (int t = 0; t < 16; ++t) {
        int p = t & 1;
        if (t < 15) {
            STAGE(t + 1, p ^ 1);
            asm volatile("s_waitcnt vmcnt(8)\ns_barrier" ::: "memory");
        } else {
            asm volatile("s_waitcnt vmcnt(0)\ns_barrier" ::: "memory");
        }
        const char* Kb = smem + p * 65536;
        const char* Vb = smem + p * 65536 + 32768;

        #pragma unroll
        for (int sg = 0; sg < 2; ++sg) {
            int srow = ss * 64 + sg * 32 + ln;
            bf16x8 ka[4];
            #pragma unroll
            for (int ks = 0; ks < 4; ++ks)
                ka[ks] = *(const bf16x8*)(Kb + srow * 128 + (((ks * 2 + hi) ^ (srow & 7)) * 16));

            f32x16 s;
            #pragma unroll
            for (int i = 0; i < 16; i++) s[i] = 0.f;
            s = MFMA32(ka[0], qf[0], s);
            s = MFMA32(ka[1], qf[1], s);
            s = MFMA32(ka[2], qf[2], s);
            s = MFMA32(ka[3], qf[3], s);

            float pv[16];
            #pragma unroll
            for (int i = 0; i < 16; i++) pv[i] = __builtin_amdgcn_exp2f(s[i]);
            float l0 = (pv[0] + pv[1]) + (pv[2] + pv[3]);
            float l1 = (pv[4] + pv[5]) + (pv[6] + pv[7]);
            float l2 = (pv[8] + pv[9]) + (pv[10] + pv[11]);
            float l3 = (pv[12] + pv[13]) + (pv[14] + pv[15]);
            lsum += (l0 + l1) + (l2 + l3);

            int d01 = pkbf(pv[0],  pv[1]),  d23 = pkbf(pv[2],  pv[3]);
            int d45 = pkbf(pv[4],  pv[5]),  d67 = pkbf(pv[6],  pv[7]);
            int e01 = pkbf(pv[8],  pv[9]),  e23 = pkbf(pv[10], pv[11]);
            int e45 = pkbf(pv[12], pv[13]), e67 = pkbf(pv[14], pv[15]);
            asm("v_permlane32_swap_b32 %0, %1" : "+v"(d01), "+v"(d45));
            asm("v_permlane32_swap_b32 %0, %1" : "+v"(d23), "+v"(d67));
            asm("v_permlane32_swap_b32 %0, %1" : "+v"(e01), "+v"(e45));
            asm("v_permlane32_swap_b32 %0, %1" : "+v"(e23), "+v"(e67));
            union F { int i[4]; bf16x8 v; } f0, f1;
            f0.i[0] = d01; f0.i[1] = d23; f0.i[2] = d45; f0.i[3] = d67;
            f1.i[0] = e01; f1.i[1] = e23; f1.i[2] = e45; f1.i[3] = e67;

            int ksp = ss * 4 + sg * 2;
            #pragma unroll
            for (int dg = 0; dg < 2; ++dg) {
                int d = dg * 32 + ln;
                bf16x8 va0 = *(const bf16x8*)(Vb + d * 512 + ((((ksp)     * 2 + hi) ^ (d & 7)) * 16));
                bf16x8 va1 = *(const bf16x8*)(Vb + d * 512 + ((((ksp + 1) * 2 + hi) ^ (d & 7)) * 16));
                if (dg == 0) { oacc0 = MFMA32(va0, f0.v, oacc0); oacc0 = MFMA32(va1, f1.v, oacc0); }
                else         { oacc1 = MFMA32(va0, f0.v, oacc1); oacc1 = MFMA32(va1, f1.v, oacc1); }
            }
        }
        asm volatile("s_waitcnt lgkmcnt(0)\ns_barrier" ::: "memory");
    }
    #undef STAGE

    lsum += __shfl_xor(lsum, 32, 64);

    float* accC = (float*)smem;                      // [16][64][20]
    float* lsC  = (float*)(smem + 102400);           // [8][32], slot = qg*4+ss
    union O { f32x16 v; f32x4 q[4]; } o0, o1;
    o0.v = oacc0; o1.v = oacc1;
    {
        int b0 = ((qg * 4 + ss) * 2 + 0) * 1280 + l * 20;
        int b1 = ((qg * 4 + ss) * 2 + 1) * 1280 + l * 20;
        #pragma unroll
        for (int g = 0; g < 4; ++g) {
            *(f32x4*)&accC[b0 + g * 4] = o0.q[g];
            *(f32x4*)&accC[b1 + g * 4] = o1.q[g];
        }
        if (l < 32) lsC[(qg * 4 + ss) * 32 + l] = lsum;
    }
    __syncthreads();

    {
        int q = tid >> 3, c8 = tid & 7;
        int qg2 = q >> 5, ln2 = q & 31;
        float ls = 0.f;
        #pragma unroll
        for (int s2 = 0; s2 < 4; ++s2) ls += lsC[(qg2 * 4 + s2) * 32 + ln2];
        float inv = 1.0f / ls;
        float vout[8];
        #pragma unroll
        for (int j = 0; j < 8; ++j) {
            int d = c8 * 8 + j;
            int hi2 = (d >> 2) & 1, dg = d >> 5;
            int r = (((d & 31) >> 3) << 2) | (d & 3);
            float sum = 0.f;
            #pragma unroll
            for (int s2 = 0; s2 < 4; ++s2)
                sum += accC[((qg2 * 4 + s2) * 2 + dg) * 1280 + (hi2 * 32 + ln2) * 20 + r];
            vout[j] = sum * inv;
        }
        float* orow = out + (size_t)(b * TT + t0 + q) * HS + c8 * 8;
        *(f32x4*)(orow)     = *(f32x4*)&vout[0];
        *(f32x4*)(orow + 4) = *(f32x4*)&vout[4];
    }
}

// ---------------- launcher --------------------------------------------------------------
extern "C" void kernel_launch(void* const* d_in, const int* in_sizes, int n_in,
                              void* d_out, int out_size, void* d_ws, size_t ws_size,
                              hipStream_t stream) {
    (void)in_sizes; (void)n_in; (void)out_size; (void)ws_size;
    const float* x   = (const float*)d_in[0];
    const float* enc = (const float*)d_in[1];
    const float* Wq  = (const float*)d_in[2];
    const float* Wk  = (const float*)d_in[3];
    const float* Wv  = (const float*)d_in[4];
    float* out = (float*)d_out;

    char* ws = (char*)d_ws;
    __bf16* wtb  = (__bf16*)ws;                            // 393216 B
    __bf16* qbuf = (__bf16*)(ws + 393216);                 // 2 MB
    __bf16* kbuf = (__bf16*)(ws + 393216 + 2097152);       // 2 MB
    __bf16* vbuf = (__bf16*)(ws + 393216 + 2 * 2097152);   // 2 MB

    hipLaunchKernelGGL(prep_wt,  dim3(768), dim3(256), 0,      stream, Wq, Wk, Wv, wtb);
    hipLaunchKernelGGL(proj_qkv, dim3(256), dim3(512), 131072, stream, x, enc, wtb, qbuf, kbuf, vbuf);
    hipLaunchKernelGGL(attn,     dim3(256), dim3(512), 131072, stream, qbuf, kbuf, vbuf, out);
}

// Round 14
// 65.035 us; speedup vs baseline: 1.6886x; 1.0856x over previous
//
#include <hip/hip_runtime.h>
#include <hip/hip_bf16.h>

#define TT 4096
#define SS 4096
#define CC 1024
#define HS 64

typedef __bf16 bf16x8 __attribute__((ext_vector_type(8)));
typedef __bf16 bf16x4 __attribute__((ext_vector_type(4)));
typedef float  f32x4  __attribute__((ext_vector_type(4)));
typedef float  f32x16 __attribute__((ext_vector_type(16)));

#define MFMA16(A,B,C) __builtin_amdgcn_mfma_f32_16x16x32_bf16((A),(B),(C),0,0,0)
#define MFMA32(A,B,C) __builtin_amdgcn_mfma_f32_32x32x16_bf16((A),(B),(C),0,0,0)

__device__ __forceinline__ int pkbf(float a, float b) {
    union { struct { __bf16 lo, hi; } h; int i; } u;
    u.h.lo = (__bf16)a; u.h.hi = (__bf16)b;
    return u.i;
}

__device__ __forceinline__ bf16x8 cvt8(float4 f0, float4 f1) {
    bf16x8 a;
    a[0] = (__bf16)f0.x; a[1] = (__bf16)f0.y; a[2] = (__bf16)f0.z; a[3] = (__bf16)f0.w;
    a[4] = (__bf16)f1.x; a[5] = (__bf16)f1.y; a[6] = (__bf16)f1.z; a[7] = (__bf16)f1.w;
    return a;
}

// fire-and-forget global->LDS, 16B per lane; LDS dest = wave-uniform base + lane*16
__device__ __forceinline__ void gload_lds16(const void* g, char* l) {
    __builtin_amdgcn_global_load_lds(
        (const __attribute__((address_space(1))) void*)g,
        (__attribute__((address_space(3))) void*)l, 16, 0, 0);
}

// ---------------- prep: W[1024][64] fp32 -> WT[64][1024] bf16 --------------------------
__global__ __launch_bounds__(256) void prep_wt(const float* __restrict__ Wq,
                                               const float* __restrict__ Wk,
                                               const float* __restrict__ Wv,
                                               __bf16* __restrict__ wt) {
    int idx = blockIdx.x * 256 + threadIdx.x;   // 3*65536 total
    int mat = idx >> 16;
    int e   = idx & 65535;
    int d   = e >> 10;
    int kk  = e & 1023;
    const float* W = (mat == 0) ? Wq : (mat == 1 ? Wk : Wv);
    float v = W[kk * HS + d];
    if (mat == 0) v *= 0.125f * 1.44269504088896340736f;
    wt[idx] = (__bf16)v;                        // wt[mat][d][kk]
}

// ---------------- QKV projection (R9 structure) + XCD-mix, default cache policy --------
// 256 blocks x 512 thr, 1 block/CU. kv = (bid>>3)&1 so BOTH input streams (x, enc)
// flow through ALL 8 XCDs. A staged with DEFAULT policy (L3 keeps ~half of x/enc
// resident across replays — NT killed that, R13 post-mortem). Block = 128 rows,
// wave w owns 16. 16 K-steps of 64. A triple-buffered (3x32KB, depth-2 prefetch),
// B double-buffered (2x16KB). Counted vmcnt + 2 barriers per step.
__global__ __launch_bounds__(512, 1) void proj_qkv(const float* __restrict__ x,
                                                   const float* __restrict__ enc,
                                                   const __bf16* __restrict__ wt,
                                                   __bf16* __restrict__ qb,
                                                   __bf16* __restrict__ kb,
                                                   __bf16* __restrict__ vt) {
    extern __shared__ char smem[];              // 131072: A 3x32K @0 ; B 2x16K @98304
    int tid = threadIdx.x;
    int w = tid >> 6, l = tid & 63, lq = l >> 4, lm = l & 15;
    int bid = blockIdx.x;
    int kv  = (bid >> 3) & 1;                   // XCD-mix: both streams on all XCDs
    int idx = ((bid >> 4) << 3) | (bid & 7);    // [0,128) per stream, bijective
    int row0 = idx * 128;
    int rowbase = row0 + w * 16;
    const float*  src   = kv ? enc : x;
    const __bf16* wbase = wt + (kv ? HS * CC : 0);
    const __bf16* wvb   = wt + 2 * HS * CC;

    // A-stage: wave w stages its own 16 rows into buffer k%3; issue j = 4 rows
    // LDS[row][g] = global[row][g^row] (g = 16B granule, 16/row) — verified pattern
    #define STAGE_A(k) do {                                                             \
        _Pragma("unroll")                                                               \
        for (int j = 0; j < 4; ++j) {                                                   \
            int rloc = j * 4 + (l >> 4);                                                \
            int gs = (l & 15) ^ rloc;                                                   \
            gload_lds16(src + (size_t)(rowbase + rloc) * CC + (k) * 64 + gs * 4,        \
                        smem + ((k) % 3) * 32768 + w * 4096 + j * 1024);                \
        }                                                                               \
    } while (0)

    // B-stage: one issue per mat; wave w stages rows w*8..w*8+7 of the 64-row wt slice
    // LDS[row][g] = global[row][g^(row&7)] (g = 16B granule, 8/row)
    #define STAGE_B(k, mptr, moff) do {                                                 \
        int gs = (l & 7) ^ (l >> 3);                                                    \
        gload_lds16(mptr + (size_t)(w * 8 + (l >> 3)) * CC + (k) * 64 + gs * 8,         \
                    smem + 98304 + ((k) & 1) * 16384 + (moff) + w * 1024);              \
    } while (0)

    f32x4 accA[4], accV[4];
    #pragma unroll
    for (int i = 0; i < 4; i++) { accA[i] = (f32x4){0.f,0.f,0.f,0.f}; accV[i] = (f32x4){0.f,0.f,0.f,0.f}; }

    if (kv) {
        // prologue: B(0)[2] A(0)[4] A(1)[4] -> 10 outstanding
        STAGE_B(0, wbase, 0); STAGE_B(0, wvb, 8192);
        STAGE_A(0); STAGE_A(1);
        #pragma unroll
        for (int k = 0; k < 16; ++k) {
            if (k < 15) { STAGE_B(k + 1, wbase, 0); STAGE_B(k + 1, wvb, 8192); }
            if (k < 14) STAGE_A(k + 2);
            // counted waits: stage(k) landed; k+1 (and A k+2) stay in flight
            if (k < 14)       asm volatile("s_waitcnt vmcnt(10)\ns_barrier" ::: "memory");
            else if (k == 14) asm volatile("s_waitcnt vmcnt(6)\ns_barrier" ::: "memory");
            else              asm volatile("s_waitcnt vmcnt(0)\ns_barrier" ::: "memory");

            const char* Ab = smem + (k % 3) * 32768 + w * 4096;
            const char* Bb = smem + 98304 + (k & 1) * 16384;
            #pragma unroll
            for (int ks = 0; ks < 2; ++ks) {
                int g0 = ks * 8 + lq * 2;
                float4 f0 = *(const float4*)(Ab + lm * 256 + ((g0)     ^ lm) * 16);
                float4 f1 = *(const float4*)(Ab + lm * 256 + ((g0 + 1) ^ lm) * 16);
                bf16x8 af = cvt8(f0, f1);
                int bg = ((ks * 4 + lq) ^ (lm & 7)) * 16;
                #pragma unroll
                for (int nt = 0; nt < 4; nt++) {
                    bf16x8 bA = *(const bf16x8*)(Bb + (nt * 16 + lm) * 128 + bg);
                    bf16x8 bV = *(const bf16x8*)(Bb + 8192 + (nt * 16 + lm) * 128 + bg);
                    accA[nt] = MFMA16(af, bA, accA[nt]);
                    accV[nt] = MFMA16(af, bV, accV[nt]);
                }
            }
            asm volatile("s_waitcnt lgkmcnt(0)\ns_barrier" ::: "memory");
        }
    } else {
        // prologue: B(0)[1] A(0)[4] A(1)[4] -> 9 outstanding
        STAGE_B(0, wbase, 0);
        STAGE_A(0); STAGE_A(1);
        #pragma unroll
        for (int k = 0; k < 16; ++k) {
            if (k < 15) STAGE_B(k + 1, wbase, 0);
            if (k < 14) STAGE_A(k + 2);
            if (k < 14)       asm volatile("s_waitcnt vmcnt(9)\ns_barrier" ::: "memory");
            else if (k == 14) asm volatile("s_waitcnt vmcnt(5)\ns_barrier" ::: "memory");
            else              asm volatile("s_waitcnt vmcnt(0)\ns_barrier" ::: "memory");

            const char* Ab = smem + (k % 3) * 32768 + w * 4096;
            const char* Bb = smem + 98304 + (k & 1) * 16384;
            #pragma unroll
            for (int ks = 0; ks < 2; ++ks) {
                int g0 = ks * 8 + lq * 2;
                float4 f0 = *(const float4*)(Ab + lm * 256 + ((g0)     ^ lm) * 16);
                float4 f1 = *(const float4*)(Ab + lm * 256 + ((g0 + 1) ^ lm) * 16);
                bf16x8 af = cvt8(f0, f1);
                int bg = ((ks * 4 + lq) ^ (lm & 7)) * 16;
                #pragma unroll
                for (int nt = 0; nt < 4; nt++) {
                    bf16x8 bA = *(const bf16x8*)(Bb + (nt * 16 + lm) * 128 + bg);
                    accA[nt] = MFMA16(af, bA, accA[nt]);
                }
            }
            asm volatile("s_waitcnt lgkmcnt(0)\ns_barrier" ::: "memory");
        }
    }
    #undef STAGE_A
    #undef STAGE_B

    // ---- epilogue q/k: D row m = lq*4+r (wave-local), col n = nt*16+lm ----
    {
        __bf16* dstA = kv ? kb : qb;
        #pragma unroll
        for (int nt = 0; nt < 4; nt++)
            #pragma unroll
            for (int r = 0; r < 4; r++)
                dstA[(size_t)(rowbase + lq * 4 + r) * HS + nt * 16 + lm] = (__bf16)accA[nt][r];
    }
    // ---- epilogue v: vt[b][d][s]; D rows are consecutive s -> 8B contiguous ----
    if (kv) {
        int bb = row0 >> 12;
        int sbase = (row0 & 4095) + w * 16 + lq * 4;
        #pragma unroll
        for (int nt = 0; nt < 4; nt++) {
            bf16x4 pk = { (__bf16)accV[nt][0], (__bf16)accV[nt][1],
                          (__bf16)accV[nt][2], (__bf16)accV[nt][3] };
            *(bf16x4*)(vt + ((size_t)bb * HS + nt * 16 + lm) * SS + sbase) = pk;
        }
    }
}

// ---------------- flash attention (unchanged from round 8 — verified, at L2 roofline) --
__global__ __launch_bounds__(512, 1) void attn(const __bf16* __restrict__ qb,
                                               const __bf16* __restrict__ kb,
                                               const __bf16* __restrict__ vt,
                                               float* __restrict__ out) {
    extern __shared__ char smem[];              // 131072 B
    int tid = threadIdx.x, w = tid >> 6, l = tid & 63;
    int hi = l >> 5, ln = l & 31;
    int qg = w & 1, ss = w >> 1;

    int bid = blockIdx.x;
    int b = bid & 3, tb = bid >> 2;             // XCD (bid%8) -> fixed batch (b=bid&3)
    int t0 = tb * 64;

    const __bf16* qp = qb + ((size_t)(b * TT + t0 + qg * 32 + ln)) * HS + hi * 8;
    bf16x8 qf[4];
    qf[0] = *(const bf16x8*)(qp);
    qf[1] = *(const bf16x8*)(qp + 16);
    qf[2] = *(const bf16x8*)(qp + 32);
    qf[3] = *(const bf16x8*)(qp + 48);

    const __bf16* kbase = kb + (size_t)b * SS * HS;   // [4096][64]
    const __bf16* vbase = vt + (size_t)b * HS * SS;   // [64][4096]

    #define STAGE(t, p) do {                                                            \
        _Pragma("unroll")                                                               \
        for (int i = 0; i < 4; ++i) {                                                   \
            int idx = i * 512 + tid;                                                    \
            int sr = idx >> 3, g = idx & 7;                                             \
            gload_lds16(kbase + ((size_t)(t) * 256 + sr) * 64 + ((g ^ (sr & 7)) * 8),   \
                        smem + (p) * 65536 + idx * 16);                                 \
        }                                                                               \
        _Pragma("unroll")                                                               \
        for (int i = 0; i < 4; ++i) {                                                   \
            int idx = i * 512 + tid;                                                    \
            int dr = idx >> 5, g = idx & 31;                                            \
            gload_lds16(vbase + (size_t)dr * SS + (t) * 256 + ((g ^ (dr & 7)) * 8),     \
                        smem + (p) * 65536 + 32768 + idx * 16);                         \
        }                                                                               \
    } while (0)

    f32x16 oacc0, oacc1;
    #pragma unroll
    for (int i = 0; i < 16; i++) { oacc0[i] = 0.f; oacc1[i] = 0.f; }
    float lsum = 0.f;

    STAGE(0, 0);
    for (int t = 0; t < 16; ++t) {
        int p = t & 1;
        if (t < 15) {
            STAGE(t + 1, p ^ 1);
            asm volatile("s_waitcnt vmcnt(8)\ns_barrier" ::: "memory");
        } else {
            asm volatile("s_waitcnt vmcnt(0)\ns_barrier" ::: "memory");
        }
        const char* Kb = smem + p * 65536;
        const char* Vb = smem + p * 65536 + 32768;

        #pragma unroll
        for (int sg = 0; sg < 2; ++sg) {
            int srow = ss * 64 + sg * 32 + ln;
            bf16x8 ka[4];
            #pragma unroll
            for (int ks = 0; ks < 4; ++ks)
                ka[ks] = *(const bf16x8*)(Kb + srow * 128 + (((ks * 2 + hi) ^ (srow & 7)) * 16));

            f32x16 s;
            #pragma unroll
            for (int i = 0; i < 16; i++) s[i] = 0.f;
            s = MFMA32(ka[0], qf[0], s);
            s = MFMA32(ka[1], qf[1], s);
            s = MFMA32(ka[2], qf[2], s);
            s = MFMA32(ka[3], qf[3], s);

            float pv[16];
            #pragma unroll
            for (int i = 0; i < 16; i++) pv[i] = __builtin_amdgcn_exp2f(s[i]);
            float l0 = (pv[0] + pv[1]) + (pv[2] + pv[3]);
            float l1 = (pv[4] + pv[5]) + (pv[6] + pv[7]);
            float l2 = (pv[8] + pv[9]) + (pv[10] + pv[11]);
            float l3 = (pv[12] + pv[13]) + (pv[14] + pv[15]);
            lsum += (l0 + l1) + (l2 + l3);

            int d01 = pkbf(pv[0],  pv[1]),  d23 = pkbf(pv[2],  pv[3]);
            int d45 = pkbf(pv[4],  pv[5]),  d67 = pkbf(pv[6],  pv[7]);
            int e01 = pkbf(pv[8],  pv[9]),  e23 = pkbf(pv[10], pv[11]);
            int e45 = pkbf(pv[12], pv[13]), e67 = pkbf(pv[14], pv[15]);
            asm("v_permlane32_swap_b32 %0, %1" : "+v"(d01), "+v"(d45));
            asm("v_permlane32_swap_b32 %0, %1" : "+v"(d23), "+v"(d67));
            asm("v_permlane32_swap_b32 %0, %1" : "+v"(e01), "+v"(e45));
            asm("v_permlane32_swap_b32 %0, %1" : "+v"(e23), "+v"(e67));
            union F { int i[4]; bf16x8 v; } f0, f1;
            f0.i[0] = d01; f0.i[1] = d23; f0.i[2] = d45; f0.i[3] = d67;
            f1.i[0] = e01; f1.i[1] = e23; f1.i[2] = e45; f1.i[3] = e67;

            int ksp = ss * 4 + sg * 2;
            #pragma unroll
            for (int dg = 0; dg < 2; ++dg) {
                int d = dg * 32 + ln;
                bf16x8 va0 = *(const bf16x8*)(Vb + d * 512 + ((((ksp)     * 2 + hi) ^ (d & 7)) * 16));
                bf16x8 va1 = *(const bf16x8*)(Vb + d * 512 + ((((ksp + 1) * 2 + hi) ^ (d & 7)) * 16));
                if (dg == 0) { oacc0 = MFMA32(va0, f0.v, oacc0); oacc0 = MFMA32(va1, f1.v, oacc0); }
                else         { oacc1 = MFMA32(va0, f0.v, oacc1); oacc1 = MFMA32(va1, f1.v, oacc1); }
            }
        }
        asm volatile("s_waitcnt lgkmcnt(0)\ns_barrier" ::: "memory");
    }
    #undef STAGE

    lsum += __shfl_xor(lsum, 32, 64);

    float* accC = (float*)smem;                      // [16][64][20]
    float* lsC  = (float*)(smem + 102400);           // [8][32], slot = qg*4+ss
    union O { f32x16 v; f32x4 q[4]; } o0, o1;
    o0.v = oacc0; o1.v = oacc1;
    {
        int b0 = ((qg * 4 + ss) * 2 + 0) * 1280 + l * 20;
        int b1 = ((qg * 4 + ss) * 2 + 1) * 1280 + l * 20;
        #pragma unroll
        for (int g = 0; g < 4; ++g) {
            *(f32x4*)&accC[b0 + g * 4] = o0.q[g];
            *(f32x4*)&accC[b1 + g * 4] = o1.q[g];
        }
        if (l < 32) lsC[(qg * 4 + ss) * 32 + l] = lsum;
    }
    __syncthreads();

    {
        int q = tid >> 3, c8 = tid & 7;
        int qg2 = q >> 5, ln2 = q & 31;
        float ls = 0.f;
        #pragma unroll
        for (int s2 = 0; s2 < 4; ++s2) ls += lsC[(qg2 * 4 + s2) * 32 + ln2];
        float inv = 1.0f / ls;
        float vout[8];
        #pragma unroll
        for (int j = 0; j < 8; ++j) {
            int d = c8 * 8 + j;
            int hi2 = (d >> 2) & 1, dg = d >> 5;
            int r = (((d & 31) >> 3) << 2) | (d & 3);
            float sum = 0.f;
            #pragma unroll
            for (int s2 = 0; s2 < 4; ++s2)
                sum += accC[((qg2 * 4 + s2) * 2 + dg) * 1280 + (hi2 * 32 + ln2) * 20 + r];
            vout[j] = sum * inv;
        }
        float* orow = out + (size_t)(b * TT + t0 + q) * HS + c8 * 8;
        *(f32x4*)(orow)     = *(f32x4*)&vout[0];
        *(f32x4*)(orow + 4) = *(f32x4*)&vout[4];
    }
}

// ---------------- launcher --------------------------------------------------------------
extern "C" void kernel_launch(void* const* d_in, const int* in_sizes, int n_in,
                              void* d_out, int out_size, void* d_ws, size_t ws_size,
                              hipStream_t stream) {
    (void)in_sizes; (void)n_in; (void)out_size; (void)ws_size;
    const float* x   = (const float*)d_in[0];
    const float* enc = (const float*)d_in[1];
    const float* Wq  = (const float*)d_in[2];
    const float* Wk  = (const float*)d_in[3];
    const float* Wv  = (const float*)d_in[4];
    float* out = (float*)d_out;

    char* ws = (char*)d_ws;
    __bf16* wtb  = (__bf16*)ws;                            // 393216 B
    __bf16* qbuf = (__bf16*)(ws + 393216);                 // 2 MB
    __bf16* kbuf = (__bf16*)(ws + 393216 + 2097152);       // 2 MB
    __bf16* vbuf = (__bf16*)(ws + 393216 + 2 * 2097152);   // 2 MB

    hipLaunchKernelGGL(prep_wt,  dim3(768), dim3(256), 0,      stream, Wq, Wk, Wv, wtb);
    hipLaunchKernelGGL(proj_qkv, dim3(256), dim3(512), 131072, stream, x, enc, wtb, qbuf, kbuf, vbuf);
    hipLaunchKernelGGL(attn,     dim3(256), dim3(512), 131072, stream, qbuf, kbuf, vbuf, out);
}